// Round 1
// baseline (404.521 us; speedup 1.0000x reference)
//
#include <hip/hip_runtime.h>
#include <math.h>

#define D 768
#define DF4 192               // D / 4
#define NQ 128                // total queries
#define KPQ 784               // keys per query
#define NCHUNK 4              // key chunks per query
#define KCHUNK 196            // KPQ / NCHUNK

__device__ __forceinline__ float dot4f(const float4 a, const float4 b) {
    return a.x * b.x + a.y * b.y + a.z * b.z + a.w * b.w;
}

// Out[q0+q][d] = bias[d] + sum_e W[d][e] * In[q0+q][e]
// (row-major W, both operands read as rows -> per-lane W stream + uniform In broadcast)
__global__ __launch_bounds__(768) void k_rowgemm(const float4* __restrict__ In,
                                                 const float4* __restrict__ W,
                                                 const float* __restrict__ bias,
                                                 float* __restrict__ Out) {
    const int d  = threadIdx.x;
    const int q0 = blockIdx.x * 8;
    const float4* wrow = W + (size_t)d * DF4;
    float acc[8] = {0.f, 0.f, 0.f, 0.f, 0.f, 0.f, 0.f, 0.f};
    for (int e4 = 0; e4 < DF4; ++e4) {
        const float4 wv = wrow[e4];
#pragma unroll
        for (int q = 0; q < 8; ++q) {
            const float4 iv = In[(q0 + q) * DF4 + e4];   // wave-uniform address
            acc[q] += dot4f(wv, iv);
        }
    }
    const float b = bias[d];
#pragma unroll
    for (int q = 0; q < 8; ++q)
        Out[(size_t)(q0 + q) * D + d] = acc[q] + b;
}

// qt[i][e] = sum_d q[i][d] * Wk[d][e]   (coalesced Wk columns across lanes)
__global__ __launch_bounds__(768) void k_qt(const float* __restrict__ qbuf,
                                            const float* __restrict__ Wk,
                                            float* __restrict__ qtbuf) {
    const int e  = threadIdx.x;
    const int q0 = blockIdx.x * 8;
    float acc[8] = {0.f, 0.f, 0.f, 0.f, 0.f, 0.f, 0.f, 0.f};
    for (int d = 0; d < D; d += 4) {
        const float w0 = Wk[(size_t)(d + 0) * D + e];
        const float w1 = Wk[(size_t)(d + 1) * D + e];
        const float w2 = Wk[(size_t)(d + 2) * D + e];
        const float w3 = Wk[(size_t)(d + 3) * D + e];
#pragma unroll
        for (int q = 0; q < 8; ++q) {
            const float4 qv = *reinterpret_cast<const float4*>(&qbuf[(size_t)(q0 + q) * D + d]); // uniform
            acc[q] = fmaf(qv.x, w0, acc[q]);
            acc[q] = fmaf(qv.y, w1, acc[q]);
            acc[q] = fmaf(qv.z, w2, acc[q]);
            acc[q] = fmaf(qv.w, w3, acc[q]);
        }
    }
#pragma unroll
    for (int q = 0; q < 8; ++q)
        qtbuf[(size_t)(q0 + q) * D + e] = acc[q];
}

// Flash pass: one block per (query, key-chunk). Online softmax over raw HR rows.
// Per-wave partial (m, l, c[768 spread 12/lane]) -> block combine -> Cpart/ML.
__global__ __launch_bounds__(512) void k_flash(const float4* __restrict__ HR,
                                               const float4* __restrict__ qt,
                                               float4* __restrict__ Cpart,
                                               float2* __restrict__ ML) {
    const int b     = blockIdx.x;
    const int qi    = b >> 2;       // / NCHUNK
    const int chunk = b & 3;
    const int n = qi >> 5, s = qi & 31;
    const size_t rowbase = (size_t)n * 25088 + (size_t)s * 784 + (size_t)chunk * KCHUNK;
    const int tid  = threadIdx.x;
    const int w    = tid >> 6;
    const int lane = tid & 63;

    const float4 qa = qt[qi * DF4 + lane];
    const float4 qb = qt[qi * DF4 + lane + 64];
    const float4 qc = qt[qi * DF4 + lane + 128];

    const float rsqrt_d = 0.036084391824351615f;   // 1/sqrt(768)

    float m = -1e30f, l = 0.f;
    float4 c0 = make_float4(0.f, 0.f, 0.f, 0.f);
    float4 c1 = make_float4(0.f, 0.f, 0.f, 0.f);
    float4 c2 = make_float4(0.f, 0.f, 0.f, 0.f);

    for (int j = w; j < KCHUNK; j += 8) {
        const float4* row = HR + (rowbase + (size_t)j) * DF4;
        const float4 r0 = row[lane];
        const float4 r1 = row[lane + 64];
        const float4 r2 = row[lane + 128];
        float p = dot4f(qa, r0) + dot4f(qb, r1) + dot4f(qc, r2);
#pragma unroll
        for (int off = 32; off > 0; off >>= 1) p += __shfl_xor(p, off, 64);
        const float sc = p * rsqrt_d;
        if (sc <= m) {                       // wave-uniform branch
            const float e = __expf(sc - m);
            l += e;
            c0.x += e * r0.x; c0.y += e * r0.y; c0.z += e * r0.z; c0.w += e * r0.w;
            c1.x += e * r1.x; c1.y += e * r1.y; c1.z += e * r1.z; c1.w += e * r1.w;
            c2.x += e * r2.x; c2.y += e * r2.y; c2.z += e * r2.z; c2.w += e * r2.w;
        } else {
            const float e = __expf(m - sc);  // first key: e = exp(-huge) = 0
            l = l * e + 1.f;
            c0.x = c0.x * e + r0.x; c0.y = c0.y * e + r0.y; c0.z = c0.z * e + r0.z; c0.w = c0.w * e + r0.w;
            c1.x = c1.x * e + r1.x; c1.y = c1.y * e + r1.y; c1.z = c1.z * e + r1.z; c1.w = c1.w * e + r1.w;
            c2.x = c2.x * e + r2.x; c2.y = c2.y * e + r2.y; c2.z = c2.z * e + r2.z; c2.w = c2.w * e + r2.w;
            m = sc;
        }
    }

    __shared__ float4 c_lds[8][DF4];
    __shared__ float  m_lds[8], l_lds[8];
    c_lds[w][lane]       = c0;
    c_lds[w][lane + 64]  = c1;
    c_lds[w][lane + 128] = c2;
    if (lane == 0) { m_lds[w] = m; l_lds[w] = l; }
    __syncthreads();

    if (tid < DF4) {
        float M = m_lds[0];
#pragma unroll
        for (int p2 = 1; p2 < 8; ++p2) M = fmaxf(M, m_lds[p2]);
        float L = 0.f;
        float4 cc = make_float4(0.f, 0.f, 0.f, 0.f);
#pragma unroll
        for (int p2 = 0; p2 < 8; ++p2) {
            const float wgt = __expf(m_lds[p2] - M);
            L += l_lds[p2] * wgt;
            const float4 cv = c_lds[p2][tid];
            cc.x += cv.x * wgt; cc.y += cv.y * wgt; cc.z += cv.z * wgt; cc.w += cv.w * wgt;
        }
        Cpart[(size_t)b * DF4 + tid] = cc;
        if (tid == 0) ML[b] = make_float2(M, L);
    }
}

// Combine NCHUNK partials per query -> normalized context Cn[qi][.]
__global__ __launch_bounds__(192) void k_combine(const float4* __restrict__ Cpart,
                                                 const float2* __restrict__ ML,
                                                 float4* __restrict__ Cn) {
    const int qi = blockIdx.x;
    const int f  = threadIdx.x;
    const float2 ml0 = ML[qi * 4 + 0];
    const float2 ml1 = ML[qi * 4 + 1];
    const float2 ml2 = ML[qi * 4 + 2];
    const float2 ml3 = ML[qi * 4 + 3];
    const float M = fmaxf(fmaxf(ml0.x, ml1.x), fmaxf(ml2.x, ml3.x));
    const float w0 = __expf(ml0.x - M), w1 = __expf(ml1.x - M);
    const float w2 = __expf(ml2.x - M), w3 = __expf(ml3.x - M);
    const float inv = 1.f / (ml0.y * w0 + ml1.y * w1 + ml2.y * w2 + ml3.y * w3);

    float4 c = make_float4(0.f, 0.f, 0.f, 0.f);
    float4 v;
    v = Cpart[(size_t)(qi * 4 + 0) * DF4 + f]; c.x += v.x * w0; c.y += v.y * w0; c.z += v.z * w0; c.w += v.w * w0;
    v = Cpart[(size_t)(qi * 4 + 1) * DF4 + f]; c.x += v.x * w1; c.y += v.y * w1; c.z += v.z * w1; c.w += v.w * w1;
    v = Cpart[(size_t)(qi * 4 + 2) * DF4 + f]; c.x += v.x * w2; c.y += v.y * w2; c.z += v.z * w2; c.w += v.w * w2;
    v = Cpart[(size_t)(qi * 4 + 3) * DF4 + f]; c.x += v.x * w3; c.y += v.y * w3; c.z += v.z * w3; c.w += v.w * w3;
    c.x *= inv; c.y *= inv; c.z *= inv; c.w *= inv;
    Cn[(size_t)qi * DF4 + f] = c;
}

// y = q + X @ Wo^T + bo, then per-row LayerNorm -> out
__global__ __launch_bounds__(768) void k_yln(const float4* __restrict__ X,
                                             const float4* __restrict__ Wo,
                                             const float* __restrict__ bo,
                                             const float* __restrict__ qbuf,
                                             const float* __restrict__ gamma,
                                             const float* __restrict__ beta,
                                             float* __restrict__ out) {
    __shared__ float y_lds[8][D];
    __shared__ float mu_lds[8], rs_lds[8];
    const int d  = threadIdx.x;
    const int q0 = blockIdx.x * 8;
    const float4* wrow = Wo + (size_t)d * DF4;
    float acc[8] = {0.f, 0.f, 0.f, 0.f, 0.f, 0.f, 0.f, 0.f};
    for (int e4 = 0; e4 < DF4; ++e4) {
        const float4 wv = wrow[e4];
#pragma unroll
        for (int q = 0; q < 8; ++q) {
            const float4 xv = X[(q0 + q) * DF4 + e4];    // uniform
            acc[q] += dot4f(wv, xv);
        }
    }
    const float b = bo[d];
#pragma unroll
    for (int q = 0; q < 8; ++q)
        y_lds[q][d] = qbuf[(size_t)(q0 + q) * D + d] + acc[q] + b;
    __syncthreads();

    const int w = d >> 6, lane = d & 63;
    if (w < 8) {
        float s = 0.f, ss = 0.f;
#pragma unroll
        for (int k = 0; k < 12; ++k) {
            const float v = y_lds[w][lane + 64 * k];
            s += v; ss += v * v;
        }
#pragma unroll
        for (int off = 32; off > 0; off >>= 1) {
            s  += __shfl_xor(s, off, 64);
            ss += __shfl_xor(ss, off, 64);
        }
        if (lane == 0) {
            const float mu  = s * (1.f / 768.f);
            const float var = ss * (1.f / 768.f) - mu * mu;
            mu_lds[w] = mu;
            rs_lds[w] = rsqrtf(var + 1e-5f);
        }
    }
    __syncthreads();

    const float g = gamma[d], be = beta[d];
#pragma unroll
    for (int q = 0; q < 8; ++q)
        out[(size_t)(q0 + q) * D + d] = (y_lds[q][d] - mu_lds[q]) * rs_lds[q] * g + be;
}

extern "C" void kernel_launch(void* const* d_in, const int* in_sizes, int n_in,
                              void* d_out, int out_size, void* d_ws, size_t ws_size,
                              hipStream_t stream) {
    const float* LR    = (const float*)d_in[0];
    const float* HR    = (const float*)d_in[1];
    const float* Wq    = (const float*)d_in[2];
    const float* bq    = (const float*)d_in[3];
    const float* Wk    = (const float*)d_in[4];
    // d_in[5] = bk: unused — adds a per-query constant to all scores (softmax-invariant)
    const float* Wv    = (const float*)d_in[6];
    const float* bv    = (const float*)d_in[7];
    const float* Wo    = (const float*)d_in[8];
    const float* bo    = (const float*)d_in[9];
    const float* gamma = (const float*)d_in[10];
    const float* beta  = (const float*)d_in[11];
    float* out = (float*)d_out;

    float* ws    = (float*)d_ws;
    float* qbuf  = ws;            // 128*768
    float* qtbuf = ws + 98304;    // 128*768
    float* Cn    = ws + 196608;   // 128*768
    float* Xbuf  = ws + 294912;   // 128*768
    float* Cpart = ws + 393216;   // 512*768
    float* ML    = ws + 786432;   // 512*2

    // q = LR @ Wq^T + bq
    k_rowgemm<<<16, 768, 0, stream>>>((const float4*)LR, (const float4*)Wq, bq, qbuf);
    // qt = q @ Wk
    k_qt<<<16, 768, 0, stream>>>(qbuf, Wk, qtbuf);
    // flash pass over HR (read HR exactly once)
    k_flash<<<NQ * NCHUNK, 512, 0, stream>>>((const float4*)HR, (const float4*)qtbuf,
                                             (float4*)Cpart, (float2*)ML);
    // combine chunk partials
    k_combine<<<NQ, 192, 0, stream>>>((const float4*)Cpart, (const float2*)ML, (float4*)Cn);
    // X = Cn @ Wv^T + bv
    k_rowgemm<<<16, 768, 0, stream>>>((const float4*)Cn, (const float4*)Wv, bv, Xbuf);
    // y = q + X @ Wo^T + bo, LayerNorm
    k_yln<<<16, 768, 0, stream>>>((const float4*)Xbuf, (const float4*)Wo, bo, qbuf,
                                  gamma, beta, out);
}

// Round 2
// 183.134 us; speedup vs baseline: 2.2089x; 2.2089x over previous
//
#include <hip/hip_runtime.h>
#include <math.h>

#define D 768
#define DF4 192               // D / 4
#define NQ 128                // total queries
#define KPQ 784               // keys per query
#define NCHUNK 16             // key chunks per query
#define KCHUNK 49             // KPQ / NCHUNK

__device__ __forceinline__ float dot4f(const float4 a, const float4 b) {
    return a.x * b.x + a.y * b.y + a.z * b.z + a.w * b.w;
}

// ---------------------------------------------------------------------------
// Fused q = LR@Wq^T + bq  and  qt = q@Wk.  One block per 2 queries.
// Phase 1: wave-per-output-row matvec (coalesced Wq float4 loads, input row in
// registers, 6-step shuffle reduce).  Phase 2: thread-per-column (coalesced Wk).
// ---------------------------------------------------------------------------
__global__ __launch_bounds__(768) void k_qqt(const float4* __restrict__ LR4,
                                             const float4* __restrict__ Wq4,
                                             const float* __restrict__ bq,
                                             const float* __restrict__ Wk,
                                             float* __restrict__ qbuf,
                                             float* __restrict__ qtbuf) {
    __shared__ __align__(16) float4 lr4[2][DF4];
    __shared__ __align__(16) float  qs[2 * D];      // interleaved: qs[2*d + r]
    const int tid  = threadIdx.x;
    const int w    = tid >> 6;
    const int lane = tid & 63;
    const int q0   = blockIdx.x * 2;

    if (tid < 2 * DF4) {
        const int r = tid / DF4, f = tid % DF4;
        lr4[r][f] = LR4[(size_t)(q0 + r) * DF4 + f];
    }
    __syncthreads();

    // preload input rows into registers (per-lane 3 x float4 slices)
    const float4 l0a = lr4[0][lane], l0b = lr4[0][lane + 64], l0c = lr4[0][lane + 128];
    const float4 l1a = lr4[1][lane], l1b = lr4[1][lane + 64], l1c = lr4[1][lane + 128];

    float my0 = 0.f, my1 = 0.f;
#pragma unroll 2
    for (int dd = 0; dd < 64; ++dd) {
        const int d = w * 64 + dd;
        const float4 w0 = Wq4[(size_t)d * DF4 + lane];
        const float4 w1 = Wq4[(size_t)d * DF4 + lane + 64];
        const float4 w2 = Wq4[(size_t)d * DF4 + lane + 128];
        float s0 = dot4f(w0, l0a) + dot4f(w1, l0b) + dot4f(w2, l0c);
        float s1 = dot4f(w0, l1a) + dot4f(w1, l1b) + dot4f(w2, l1c);
#pragma unroll
        for (int off = 32; off; off >>= 1) {
            s0 += __shfl_xor(s0, off, 64);
            s1 += __shfl_xor(s1, off, 64);
        }
        my0 = (lane == dd) ? s0 : my0;
        my1 = (lane == dd) ? s1 : my1;
    }
    {
        const int d = w * 64 + lane;
        const float b = bq[d];
        qs[2 * d + 0] = my0 + b;
        qs[2 * d + 1] = my1 + b;
    }
    __syncthreads();

    // q to global (residual input for epilogue)
    qbuf[(size_t)(q0 + 0) * D + tid] = qs[2 * tid + 0];
    qbuf[(size_t)(q0 + 1) * D + tid] = qs[2 * tid + 1];

    // phase 2: qt[e] = sum_d q[d] * Wk[d][e]  (coalesced columns)
    float a0 = 0.f, a1 = 0.f;
#pragma unroll 8
    for (int d2 = 0; d2 < D; ++d2) {
        const float2 qv = *(const float2*)&qs[2 * d2];   // uniform LDS broadcast
        const float wk = Wk[(size_t)d2 * D + tid];
        a0 = fmaf(qv.x, wk, a0);
        a1 = fmaf(qv.y, wk, a1);
    }
    qtbuf[(size_t)(q0 + 0) * D + tid] = a0;
    qtbuf[(size_t)(q0 + 1) * D + tid] = a1;
}

// ---------------------------------------------------------------------------
// Flash pass: one block per (query, key-chunk of 49).  Branch-free online
// softmax, 2-row unroll per wave (6 loads in flight).  HR read exactly once.
// ---------------------------------------------------------------------------
__global__ __launch_bounds__(256) void k_flash(const float4* __restrict__ HR,
                                               const float4* __restrict__ qt,
                                               float4* __restrict__ Cpart,
                                               float2* __restrict__ ML) {
    const int b     = blockIdx.x;
    const int qi    = b >> 4;
    const int chunk = b & 15;
    const size_t rowbase = (size_t)qi * KPQ + (size_t)chunk * KCHUNK;
    const int tid  = threadIdx.x;
    const int w    = tid >> 6;
    const int lane = tid & 63;

    const float4 qa = qt[qi * DF4 + lane];
    const float4 qb = qt[qi * DF4 + lane + 64];
    const float4 qc = qt[qi * DF4 + lane + 128];
    const float rsd = 0.036084391824351615f;   // 1/sqrt(768)

    float m = -1e30f, l = 0.f;
    float4 c0 = make_float4(0.f, 0.f, 0.f, 0.f);
    float4 c1 = make_float4(0.f, 0.f, 0.f, 0.f);
    float4 c2 = make_float4(0.f, 0.f, 0.f, 0.f);

    int j = w;
    while (j + 4 < KCHUNK) {
        const float4* rowA = HR + (rowbase + (size_t)j) * DF4;
        const float4* rowB = HR + (rowbase + (size_t)(j + 4)) * DF4;
        const float4 a0 = rowA[lane], a1 = rowA[lane + 64], a2 = rowA[lane + 128];
        const float4 b0 = rowB[lane], b1 = rowB[lane + 64], b2 = rowB[lane + 128];
        float p1 = dot4f(qa, a0) + dot4f(qb, a1) + dot4f(qc, a2);
        float p2 = dot4f(qa, b0) + dot4f(qb, b1) + dot4f(qc, b2);
#pragma unroll
        for (int off = 32; off; off >>= 1) {
            p1 += __shfl_xor(p1, off, 64);
            p2 += __shfl_xor(p2, off, 64);
        }
        p1 *= rsd; p2 *= rsd;
        const float mn = fmaxf(m, fmaxf(p1, p2));
        const float ea = __expf(m - mn);
        const float e1 = __expf(p1 - mn);
        const float e2 = __expf(p2 - mn);
        l = l * ea + e1 + e2;
        c0.x = fmaf(c0.x, ea, fmaf(e1, a0.x, e2 * b0.x));
        c0.y = fmaf(c0.y, ea, fmaf(e1, a0.y, e2 * b0.y));
        c0.z = fmaf(c0.z, ea, fmaf(e1, a0.z, e2 * b0.z));
        c0.w = fmaf(c0.w, ea, fmaf(e1, a0.w, e2 * b0.w));
        c1.x = fmaf(c1.x, ea, fmaf(e1, a1.x, e2 * b1.x));
        c1.y = fmaf(c1.y, ea, fmaf(e1, a1.y, e2 * b1.y));
        c1.z = fmaf(c1.z, ea, fmaf(e1, a1.z, e2 * b1.z));
        c1.w = fmaf(c1.w, ea, fmaf(e1, a1.w, e2 * b1.w));
        c2.x = fmaf(c2.x, ea, fmaf(e1, a2.x, e2 * b2.x));
        c2.y = fmaf(c2.y, ea, fmaf(e1, a2.y, e2 * b2.y));
        c2.z = fmaf(c2.z, ea, fmaf(e1, a2.z, e2 * b2.z));
        c2.w = fmaf(c2.w, ea, fmaf(e1, a2.w, e2 * b2.w));
        m = mn;
        j += 8;
    }
    if (j < KCHUNK) {
        const float4* rowA = HR + (rowbase + (size_t)j) * DF4;
        const float4 a0 = rowA[lane], a1 = rowA[lane + 64], a2 = rowA[lane + 128];
        float p1 = dot4f(qa, a0) + dot4f(qb, a1) + dot4f(qc, a2);
#pragma unroll
        for (int off = 32; off; off >>= 1) p1 += __shfl_xor(p1, off, 64);
        p1 *= rsd;
        const float mn = fmaxf(m, p1);
        const float ea = __expf(m - mn);
        const float e1 = __expf(p1 - mn);
        l = l * ea + e1;
        c0.x = fmaf(c0.x, ea, e1 * a0.x); c0.y = fmaf(c0.y, ea, e1 * a0.y);
        c0.z = fmaf(c0.z, ea, e1 * a0.z); c0.w = fmaf(c0.w, ea, e1 * a0.w);
        c1.x = fmaf(c1.x, ea, e1 * a1.x); c1.y = fmaf(c1.y, ea, e1 * a1.y);
        c1.z = fmaf(c1.z, ea, e1 * a1.z); c1.w = fmaf(c1.w, ea, e1 * a1.w);
        c2.x = fmaf(c2.x, ea, e1 * a2.x); c2.y = fmaf(c2.y, ea, e1 * a2.y);
        c2.z = fmaf(c2.z, ea, e1 * a2.z); c2.w = fmaf(c2.w, ea, e1 * a2.w);
        m = mn;
    }

    __shared__ __align__(16) float4 c_lds[4][DF4];
    __shared__ float m_lds[4], l_lds[4];
    c_lds[w][lane]       = c0;
    c_lds[w][lane + 64]  = c1;
    c_lds[w][lane + 128] = c2;
    if (lane == 0) { m_lds[w] = m; l_lds[w] = l; }
    __syncthreads();

    if (tid < DF4) {
        float M = fmaxf(fmaxf(m_lds[0], m_lds[1]), fmaxf(m_lds[2], m_lds[3]));
        float L = 0.f;
        float4 cc = make_float4(0.f, 0.f, 0.f, 0.f);
#pragma unroll
        for (int p = 0; p < 4; ++p) {
            const float wg = __expf(m_lds[p] - M);
            L += l_lds[p] * wg;
            const float4 cv = c_lds[p][tid];
            cc.x += cv.x * wg; cc.y += cv.y * wg; cc.z += cv.z * wg; cc.w += cv.w * wg;
        }
        Cpart[(size_t)b * DF4 + tid] = cc;
        if (tid == 0) ML[b] = make_float2(M, L);
    }
}

// ---------------------------------------------------------------------------
// Fused epilogue: combine chunk partials -> Cn; X = Cn@Wv^T + bv;
// y = q + X@Wo^T + bo; LayerNorm.  One block per 2 queries.
// ---------------------------------------------------------------------------
__global__ __launch_bounds__(768) void k_wvo_ln(const float* __restrict__ Cpart,
                                                const float2* __restrict__ ML,
                                                const float4* __restrict__ Wv,
                                                const float* __restrict__ bv,
                                                const float4* __restrict__ Wo,
                                                const float* __restrict__ bo,
                                                const float* __restrict__ qbuf,
                                                const float* __restrict__ gamma,
                                                const float* __restrict__ beta,
                                                float* __restrict__ out) {
    __shared__ __align__(16) float cnf[2][D];
    __shared__ __align__(16) float xs[2][D];
    __shared__ __align__(16) float yl[2][D];
    __shared__ float mu_s[2], rs_s[2];
    const int tid  = threadIdx.x;
    const int w    = tid >> 6;
    const int lane = tid & 63;
    const int q0   = blockIdx.x * 2;

    // combine NCHUNK partials per query (normalized context)
#pragma unroll
    for (int r = 0; r < 2; ++r) {
        float mmax = -1e30f;
        float2 mls[NCHUNK];
#pragma unroll
        for (int p = 0; p < NCHUNK; ++p) {
            mls[p] = ML[(q0 + r) * NCHUNK + p];
            mmax = fmaxf(mmax, mls[p].x);
        }
        float L = 0.f, cc = 0.f;
#pragma unroll
        for (int p = 0; p < NCHUNK; ++p) {
            const float wg = __expf(mls[p].x - mmax);
            L += mls[p].y * wg;
            cc += wg * Cpart[(size_t)((q0 + r) * NCHUNK + p) * D + tid];
        }
        cnf[r][tid] = cc / L;
    }
    __syncthreads();

    // X = Cn @ Wv^T + bv
    {
        const float4* cn4 = (const float4*)cnf;
        const float4 i0a = cn4[lane],       i0b = cn4[lane + 64],       i0c = cn4[lane + 128];
        const float4 i1a = cn4[DF4 + lane], i1b = cn4[DF4 + lane + 64], i1c = cn4[DF4 + lane + 128];
        float mx0 = 0.f, mx1 = 0.f;
#pragma unroll 2
        for (int dd = 0; dd < 64; ++dd) {
            const int d = w * 64 + dd;
            const float4 w0 = Wv[(size_t)d * DF4 + lane];
            const float4 w1 = Wv[(size_t)d * DF4 + lane + 64];
            const float4 w2 = Wv[(size_t)d * DF4 + lane + 128];
            float s0 = dot4f(w0, i0a) + dot4f(w1, i0b) + dot4f(w2, i0c);
            float s1 = dot4f(w0, i1a) + dot4f(w1, i1b) + dot4f(w2, i1c);
#pragma unroll
            for (int off = 32; off; off >>= 1) {
                s0 += __shfl_xor(s0, off, 64);
                s1 += __shfl_xor(s1, off, 64);
            }
            mx0 = (lane == dd) ? s0 : mx0;
            mx1 = (lane == dd) ? s1 : mx1;
        }
        const int d = w * 64 + lane;
        const float b = bv[d];
        xs[0][d] = mx0 + b;
        xs[1][d] = mx1 + b;
    }
    __syncthreads();

    // y = q + X @ Wo^T + bo
    {
        const float4* x4 = (const float4*)xs;
        const float4 i0a = x4[lane],       i0b = x4[lane + 64],       i0c = x4[lane + 128];
        const float4 i1a = x4[DF4 + lane], i1b = x4[DF4 + lane + 64], i1c = x4[DF4 + lane + 128];
        float my0 = 0.f, my1 = 0.f;
#pragma unroll 2
        for (int dd = 0; dd < 64; ++dd) {
            const int d = w * 64 + dd;
            const float4 w0 = Wo[(size_t)d * DF4 + lane];
            const float4 w1 = Wo[(size_t)d * DF4 + lane + 64];
            const float4 w2 = Wo[(size_t)d * DF4 + lane + 128];
            float s0 = dot4f(w0, i0a) + dot4f(w1, i0b) + dot4f(w2, i0c);
            float s1 = dot4f(w0, i1a) + dot4f(w1, i1b) + dot4f(w2, i1c);
#pragma unroll
            for (int off = 32; off; off >>= 1) {
                s0 += __shfl_xor(s0, off, 64);
                s1 += __shfl_xor(s1, off, 64);
            }
            my0 = (lane == dd) ? s0 : my0;
            my1 = (lane == dd) ? s1 : my1;
        }
        const int d = w * 64 + lane;
        const float b = bo[d];
        yl[0][d] = my0 + qbuf[(size_t)(q0 + 0) * D + d] + b;
        yl[1][d] = my1 + qbuf[(size_t)(q0 + 1) * D + d] + b;
    }
    __syncthreads();

    if (w < 2) {
        float s = 0.f, ss = 0.f;
#pragma unroll
        for (int k = 0; k < 12; ++k) {
            const float v = yl[w][lane + 64 * k];
            s += v; ss += v * v;
        }
#pragma unroll
        for (int off = 32; off; off >>= 1) {
            s  += __shfl_xor(s, off, 64);
            ss += __shfl_xor(ss, off, 64);
        }
        if (lane == 0) {
            const float mu  = s * (1.f / 768.f);
            const float var = ss * (1.f / 768.f) - mu * mu;
            mu_s[w] = mu;
            rs_s[w] = rsqrtf(var + 1e-5f);
        }
    }
    __syncthreads();

    const float g = gamma[tid], be = beta[tid];
    out[(size_t)(q0 + 0) * D + tid] = (yl[0][tid] - mu_s[0]) * rs_s[0] * g + be;
    out[(size_t)(q0 + 1) * D + tid] = (yl[1][tid] - mu_s[1]) * rs_s[1] * g + be;
}

extern "C" void kernel_launch(void* const* d_in, const int* in_sizes, int n_in,
                              void* d_out, int out_size, void* d_ws, size_t ws_size,
                              hipStream_t stream) {
    const float* LR    = (const float*)d_in[0];
    const float* HR    = (const float*)d_in[1];
    const float* Wq    = (const float*)d_in[2];
    const float* bq    = (const float*)d_in[3];
    const float* Wk    = (const float*)d_in[4];
    // d_in[5] = bk: unused (adds per-query constant to all scores; softmax-invariant)
    const float* Wv    = (const float*)d_in[6];
    const float* bv    = (const float*)d_in[7];
    const float* Wo    = (const float*)d_in[8];
    const float* bo    = (const float*)d_in[9];
    const float* gamma = (const float*)d_in[10];
    const float* beta  = (const float*)d_in[11];
    float* out = (float*)d_out;

    float* ws    = (float*)d_ws;
    float* qbuf  = ws;              // 128*768
    float* qtbuf = ws + 98304;      // 128*768
    float* Cpart = ws + 196608;     // 2048*768
    float* ML    = ws + 1769472;    // 2048*2

    k_qqt<<<NQ / 2, 768, 0, stream>>>((const float4*)LR, (const float4*)Wq, bq, Wk,
                                      qbuf, qtbuf);
    k_flash<<<NQ * NCHUNK, 256, 0, stream>>>((const float4*)HR, (const float4*)qtbuf,
                                             (float4*)Cpart, (float2*)ML);
    k_wvo_ln<<<NQ / 2, 768, 0, stream>>>(Cpart, (const float2*)ML,
                                         (const float4*)Wv, bv, (const float4*)Wo, bo,
                                         qbuf, gamma, beta, out);
}